// Round 3
// baseline (1753.663 us; speedup 1.0000x reference)
//
#include <hip/hip_runtime.h>

// SingleHeadAttention: B=4, T=4096, C=1024, causal. fp32 in/out, bf16 MFMA internally.
// Pipeline: [gemm_bt qkv] -> [transpose v] -> [flash attention v2] -> [gemm_bt out]
// ws (bf16): qkv[16384][3072] | vT[4][1024][4096] | ao[16384][1024]  = 160 MB

typedef unsigned short u16;
typedef float f32x4 __attribute__((ext_vector_type(4)));
typedef __bf16 bf16x8 __attribute__((ext_vector_type(8)));

__device__ __forceinline__ u16 f2bf(float f) {
  __bf16 h = (__bf16)f;
  return __builtin_bit_cast(u16, h);
}

// ---------------------------------------------------------------------------
// C[M][N] = A[M][K] @ B[N][K]^T  (bf16 MFMA, fp32 accumulate). TA/TB/TC are
// float or u16(bf16); fp32 sources are converted to bf16 during LDS staging.
// ---------------------------------------------------------------------------
template <typename TA, typename TB, typename TC>
__global__ __launch_bounds__(256) void gemm_bt(const TA* __restrict__ A,
                                               const TB* __restrict__ B,
                                               TC* __restrict__ C,
                                               int M, int N, int K) {
  constexpr int LDT = 40;
  __shared__ u16 As[128 * LDT];
  __shared__ u16 Bs[128 * LDT];
  const int tid = threadIdx.x;
  const int lane = tid & 63, wv = tid >> 6;
  const int l15 = lane & 15, l4 = lane >> 4;
  const int bm = blockIdx.y * 128, bn = blockIdx.x * 128;
  const int wm = (wv >> 1) * 64, wn = (wv & 1) * 64;
  const int srow = tid >> 1, scol = (tid & 1) * 16;
  const TA* ag = A + (size_t)(bm + srow) * K + scol;
  const TB* bg = B + (size_t)(bn + srow) * K + scol;

  float4 paf[4], pbf[4];
  uint4 pau[2], pbu[2];

  auto loadA = [&](int off) {
    if constexpr (sizeof(TA) == 4) {
#pragma unroll
      for (int i = 0; i < 4; ++i) paf[i] = *(const float4*)((const float*)ag + off + 4 * i);
    } else {
      pau[0] = *(const uint4*)((const u16*)ag + off);
      pau[1] = *(const uint4*)((const u16*)ag + off + 8);
    }
  };
  auto loadB = [&](int off) {
    if constexpr (sizeof(TB) == 4) {
#pragma unroll
      for (int i = 0; i < 4; ++i) pbf[i] = *(const float4*)((const float*)bg + off + 4 * i);
    } else {
      pbu[0] = *(const uint4*)((const u16*)bg + off);
      pbu[1] = *(const uint4*)((const u16*)bg + off + 8);
    }
  };
  auto storeA = [&](u16* dst) {
    if constexpr (sizeof(TA) == 4) {
      u16 t[16];
#pragma unroll
      for (int i = 0; i < 4; ++i) {
        t[i * 4 + 0] = f2bf(paf[i].x); t[i * 4 + 1] = f2bf(paf[i].y);
        t[i * 4 + 2] = f2bf(paf[i].z); t[i * 4 + 3] = f2bf(paf[i].w);
      }
      *(uint4*)dst = *(const uint4*)&t[0];
      *(uint4*)(dst + 8) = *(const uint4*)&t[8];
    } else {
      *(uint4*)dst = pau[0];
      *(uint4*)(dst + 8) = pau[1];
    }
  };
  auto storeB = [&](u16* dst) {
    if constexpr (sizeof(TB) == 4) {
      u16 t[16];
#pragma unroll
      for (int i = 0; i < 4; ++i) {
        t[i * 4 + 0] = f2bf(pbf[i].x); t[i * 4 + 1] = f2bf(pbf[i].y);
        t[i * 4 + 2] = f2bf(pbf[i].z); t[i * 4 + 3] = f2bf(pbf[i].w);
      }
      *(uint4*)dst = *(const uint4*)&t[0];
      *(uint4*)(dst + 8) = *(const uint4*)&t[8];
    } else {
      *(uint4*)dst = pbu[0];
      *(uint4*)(dst + 8) = pbu[1];
    }
  };

  f32x4 acc[4][4] = {};
  loadA(0);
  loadB(0);

  for (int k0 = 0; k0 < K; k0 += 32) {
    __syncthreads();
    storeA(&As[srow * LDT + scol]);
    storeB(&Bs[srow * LDT + scol]);
    __syncthreads();
    if (k0 + 32 < K) {
      loadA(k0 + 32);
      loadB(k0 + 32);
    }
    bf16x8 af[4], bfr[4];
#pragma unroll
    for (int t = 0; t < 4; ++t)
      af[t] = *(const bf16x8*)&As[(wm + t * 16 + l15) * LDT + l4 * 8];
#pragma unroll
    for (int t = 0; t < 4; ++t)
      bfr[t] = *(const bf16x8*)&Bs[(wn + t * 16 + l15) * LDT + l4 * 8];
#pragma unroll
    for (int mt = 0; mt < 4; ++mt)
#pragma unroll
      for (int nt = 0; nt < 4; ++nt)
        acc[mt][nt] = __builtin_amdgcn_mfma_f32_16x16x32_bf16(af[mt], bfr[nt], acc[mt][nt], 0, 0, 0);
  }

#pragma unroll
  for (int mt = 0; mt < 4; ++mt)
#pragma unroll
    for (int nt = 0; nt < 4; ++nt) {
      const int row = bm + wm + mt * 16 + l4 * 4;
      const int col = bn + wn + nt * 16 + l15;
#pragma unroll
      for (int r = 0; r < 4; ++r) {
        if constexpr (sizeof(TC) == 4)
          C[(size_t)(row + r) * N + col] = acc[mt][nt][r];
        else
          C[(size_t)(row + r) * N + col] = f2bf(acc[mt][nt][r]);
      }
    }
}

// ---------------------------------------------------------------------------
// vT[b][c][s] = qkv[b*T + s][2048 + c]   (64x64 LDS tiles, bf16)
// ---------------------------------------------------------------------------
__global__ __launch_bounds__(256) void transpose_v(const u16* __restrict__ qkv,
                                                   u16* __restrict__ vT) {
  __shared__ u16 Ts[64][72];
  const int b = blockIdx.z;
  const int s0 = blockIdx.x * 64, c0 = blockIdx.y * 64;
  const int tid = threadIdx.x;
#pragma unroll
  for (int i = 0; i < 2; ++i) {
    const int k = tid + 256 * i;
    const int sr = k >> 3, c8 = (k & 7) * 8;
    uint4 val = *(const uint4*)(qkv + ((size_t)(b * 4096 + s0 + sr)) * 3072 + 2048 + c0 + c8);
    const u16* e = (const u16*)&val;
#pragma unroll
    for (int j = 0; j < 8; ++j) Ts[c8 + j][sr] = e[j];
  }
  __syncthreads();
#pragma unroll
  for (int i = 0; i < 2; ++i) {
    const int k = tid + 256 * i;
    const int cr = k >> 3, s8 = (k & 7) * 8;
    uint4 val = *(const uint4*)&Ts[cr][s8];
    *(uint4*)(vT + ((size_t)b * 1024 + c0 + cr) * 4096 + s0 + s8) = val;
  }
}

// ---------------------------------------------------------------------------
// Flash attention v2 — GEMM-structured. 512 thr (8 waves), 1 WG per (b, 64-row
// Q-tile), key tile BN=256.
//  Phase 1: S[64][256] = Q @ K^T as LDS-staged GEMM (BK=64, reg prefetch).
//           Wave (wr,wc) owns S rows [32wr..+32) x cols [64wc..+64).
//  Phase 2: S -> Sbuf (f32 LDS) -> online softmax, 8 rows/wave, swizzled
//           column access (conflict-free), P (bf16) + alpha to LDS.
//  Phase 3: rescale O; PV: wave ds owns O[64 x 128-wide D-slice]; P from LDS
//           (A-layout), V from global vT (B-layout).
// ---------------------------------------------------------------------------
__global__ __launch_bounds__(512, 2) void flash_attn(const u16* __restrict__ qkv,
                                                     const u16* __restrict__ vT,
                                                     u16* __restrict__ ao) {
  __shared__ u16 Qs[64][72];       //  9.2 KB
  __shared__ u16 Ks[256][72];      // 36.9 KB
  __shared__ float Sbuf[64][260];  // 66.6 KB
  __shared__ u16 Pb[64][264];      // 33.8 KB
  __shared__ float Al[64];         // total ~146.7 KB -> 1 WG/CU

  const int tid = threadIdx.x;
  const int lane = tid & 63, wid = tid >> 6;
  const int l15 = lane & 15, l4 = lane >> 4;
  const int wr = wid >> 2, wc = wid & 3;            // S-GEMM role
  const int rs = lane >> 3, cb = lane & 7;          // softmax role
  const int cbp = (cb + rs) & 7;                    // bank swizzle
  const int b = blockIdx.x & 3;
  const int qt = 63 - (blockIdx.x >> 2);            // LPT: big Q-tiles first
  const int t0 = qt * 64;
  const int lr = 8 * wid + rs;                      // softmax-owned local row
  const int rowg = t0 + lr;
  const size_t base = (size_t)b * 4096;

  const int qrow = tid >> 3, qcol = (tid & 7) * 8;  // Q stage: 64x64
  const int krow = tid >> 1, kcol = (tid & 1) * 32; // K stage: 256x64
  const u16* qg = qkv + (base + t0 + qrow) * 3072 + qcol;
  const u16* kg = qkv + (base + krow) * 3072 + 1024 + kcol;
  const u16* vTb = vT + (size_t)b * 1024 * 4096;

  const int ntiles = (t0 + 64 + 255) / 256;

  f32x4 acc[4][8] = {};   // O: rows rg*16+l4*4+r, cols wid*128+nt*16+l15
  float m_run = -1e30f, l_run = 0.0f;

  uint4 pq, pk[4];
  pq = *(const uint4*)(qg);
#pragma unroll
  for (int i = 0; i < 4; ++i) pk[i] = *(const uint4*)(kg + 8 * i);

  for (int tile = 0; tile < ntiles; ++tile) {
    const int ks0 = tile * 256;
    f32x4 sacc[2][4] = {};

    // ---- Phase 1: S = Q @ K^T over D, BK=64 ----
    for (int dc = 0; dc < 16; ++dc) {
      __syncthreads();
      *(uint4*)&Qs[qrow][qcol] = pq;
#pragma unroll
      for (int i = 0; i < 4; ++i) *(uint4*)&Ks[krow][kcol + 8 * i] = pk[i];
      __syncthreads();
      {
        const int dn = dc + 1;
        size_t qoff, koff;
        if (dn < 16) {
          qoff = (size_t)dn * 64;
          koff = (size_t)ks0 * 3072 + (size_t)dn * 64;
        } else {
          qoff = 0;
          const int ksn = (tile + 1 < ntiles) ? (ks0 + 256) : 0;
          koff = (size_t)ksn * 3072;
        }
        pq = *(const uint4*)(qg + qoff);
#pragma unroll
        for (int i = 0; i < 4; ++i) pk[i] = *(const uint4*)(kg + koff + 8 * i);
      }
      bf16x8 af[2][2];
#pragma unroll
      for (int rg = 0; rg < 2; ++rg)
#pragma unroll
        for (int kb = 0; kb < 2; ++kb)
          af[rg][kb] = *(const bf16x8*)&Qs[wr * 32 + rg * 16 + l15][kb * 32 + l4 * 8];
#pragma unroll
      for (int nt = 0; nt < 4; ++nt) {
        bf16x8 bv0 = *(const bf16x8*)&Ks[wc * 64 + nt * 16 + l15][l4 * 8];
        bf16x8 bv1 = *(const bf16x8*)&Ks[wc * 64 + nt * 16 + l15][32 + l4 * 8];
#pragma unroll
        for (int rg = 0; rg < 2; ++rg) {
          sacc[rg][nt] = __builtin_amdgcn_mfma_f32_16x16x32_bf16(af[rg][0], bv0, sacc[rg][nt], 0, 0, 0);
          sacc[rg][nt] = __builtin_amdgcn_mfma_f32_16x16x32_bf16(af[rg][1], bv1, sacc[rg][nt], 0, 0, 0);
        }
      }
    }

    // ---- S -> Sbuf ----
#pragma unroll
    for (int rg = 0; rg < 2; ++rg)
#pragma unroll
      for (int nt = 0; nt < 4; ++nt)
#pragma unroll
        for (int r = 0; r < 4; ++r)
          Sbuf[wr * 32 + rg * 16 + l4 * 4 + r][wc * 64 + nt * 16 + l15] = sacc[rg][nt][r];
    __syncthreads();

    // ---- Phase 2: online softmax, 8 rows per wave ----
    {
      const float scale = 0.03125f;  // 1/sqrt(1024)
      float4 sv[8];
      float mt_ = -1e30f;
      const float4* srow = (const float4*)&Sbuf[lr][0];
#pragma unroll
      for (int t = 0; t < 8; ++t) {
        float4 v = srow[cbp + 8 * t];
        const int c0 = ks0 + 4 * (cbp + 8 * t);
        v.x = (c0 + 0 <= rowg) ? v.x * scale : -1e30f;
        v.y = (c0 + 1 <= rowg) ? v.y * scale : -1e30f;
        v.z = (c0 + 2 <= rowg) ? v.z * scale : -1e30f;
        v.w = (c0 + 3 <= rowg) ? v.w * scale : -1e30f;
        sv[t] = v;
        mt_ = fmaxf(mt_, fmaxf(fmaxf(v.x, v.y), fmaxf(v.z, v.w)));
      }
      mt_ = fmaxf(mt_, __shfl_xor(mt_, 1));
      mt_ = fmaxf(mt_, __shfl_xor(mt_, 2));
      mt_ = fmaxf(mt_, __shfl_xor(mt_, 4));
      const float mn = fmaxf(m_run, mt_);
      const float al = __expf(m_run - mn);
      m_run = mn;
      float ls = 0.0f;
#pragma unroll
      for (int t = 0; t < 8; ++t) {
        const float4 v = sv[t];
        const float p0 = __expf(v.x - mn), p1 = __expf(v.y - mn);
        const float p2 = __expf(v.z - mn), p3 = __expf(v.w - mn);
        ls += (p0 + p1) + (p2 + p3);
        u16 pw[4] = {f2bf(p0), f2bf(p1), f2bf(p2), f2bf(p3)};
        *(uint2*)&Pb[lr][4 * (cbp + 8 * t)] = *(const uint2*)pw;
      }
      ls += __shfl_xor(ls, 1);
      ls += __shfl_xor(ls, 2);
      ls += __shfl_xor(ls, 4);
      l_run = al * l_run + ls;
      if (cb == 0) Al[lr] = al;
    }
    __syncthreads();

    // ---- Phase 3: rescale O, then PV ----
    {
      float avv[4][4];
      int need = 0;
#pragma unroll
      for (int rg = 0; rg < 4; ++rg) {
        const float4 a4 = *(const float4*)&Al[rg * 16 + l4 * 4];
        avv[rg][0] = a4.x; avv[rg][1] = a4.y; avv[rg][2] = a4.z; avv[rg][3] = a4.w;
        need |= (a4.x != 1.0f) | (a4.y != 1.0f) | (a4.z != 1.0f) | (a4.w != 1.0f);
      }
      if (__any(need)) {
#pragma unroll
        for (int rg = 0; rg < 4; ++rg)
#pragma unroll
          for (int nt = 0; nt < 8; ++nt)
#pragma unroll
            for (int r = 0; r < 4; ++r) acc[rg][nt][r] *= avv[rg][r];
      }
#pragma unroll
      for (int kb = 0; kb < 8; ++kb) {
        bf16x8 pf[4];
#pragma unroll
        for (int rg = 0; rg < 4; ++rg)
          pf[rg] = *(const bf16x8*)&Pb[rg * 16 + l15][kb * 32 + l4 * 8];
#pragma unroll
        for (int nt = 0; nt < 8; ++nt) {
          const bf16x8 vf = *(const bf16x8*)(vTb + ((size_t)(wid * 128 + nt * 16 + l15)) * 4096 +
                                             ks0 + kb * 32 + l4 * 8);
#pragma unroll
          for (int rg = 0; rg < 4; ++rg)
            acc[rg][nt] = __builtin_amdgcn_mfma_f32_16x16x32_bf16(pf[rg], vf, acc[rg][nt], 0, 0, 0);
        }
      }
    }
  }

  // ---- epilogue: O / l ----
  __syncthreads();
  if (cb == 0) Al[lr] = 1.0f / l_run;
  __syncthreads();
  float ivv[4][4];
#pragma unroll
  for (int rg = 0; rg < 4; ++rg) {
    const float4 a4 = *(const float4*)&Al[rg * 16 + l4 * 4];
    ivv[rg][0] = a4.x; ivv[rg][1] = a4.y; ivv[rg][2] = a4.z; ivv[rg][3] = a4.w;
  }
#pragma unroll
  for (int rg = 0; rg < 4; ++rg)
#pragma unroll
    for (int nt = 0; nt < 8; ++nt) {
      const size_t rbase = (base + t0 + rg * 16 + l4 * 4) * 1024 + wid * 128 + nt * 16 + l15;
#pragma unroll
      for (int r = 0; r < 4; ++r)
        ao[rbase + (size_t)r * 1024] = f2bf(acc[rg][nt][r] * ivv[rg][r]);
    }
}

// ---------------------------------------------------------------------------
extern "C" void kernel_launch(void* const* d_in, const int* in_sizes, int n_in,
                              void* d_out, int out_size, void* d_ws, size_t ws_size,
                              hipStream_t stream) {
  const float* x     = (const float*)d_in[0];   // [4,4096,1024] fp32
  // d_in[1] = causal mask: ignored (computed analytically)
  const float* w_qkv = (const float*)d_in[2];   // [3072,1024] fp32
  const float* w_out = (const float*)d_in[3];   // [1024,1024] fp32
  float* out = (float*)d_out;                   // [4,4096,1024] fp32

  u16* qkv = (u16*)d_ws;                        // 16384*3072 bf16
  u16* vT  = qkv + (size_t)16384 * 3072;        // 4*1024*4096 bf16
  u16* ao  = vT + (size_t)4 * 1024 * 4096;      // 16384*1024 bf16

  gemm_bt<float, float, u16><<<dim3(24, 128), 256, 0, stream>>>(x, w_qkv, qkv, 16384, 3072, 1024);
  transpose_v<<<dim3(64, 16, 4), 256, 0, stream>>>(qkv, vT);
  flash_attn<<<dim3(256), 512, 0, stream>>>(qkv, vT, ao);
  gemm_bt<u16, float, float><<<dim3(8, 128), 256, 0, stream>>>(ao, w_out, out, 16384, 1024, 1024);
}

// Round 4
// 1653.279 us; speedup vs baseline: 1.0607x; 1.0607x over previous
//
#include <hip/hip_runtime.h>

// SingleHeadAttention: B=4, T=4096, C=1024, causal. fp32 in/out, bf16 MFMA internally.
// Pipeline: [gemm_bt qkv] -> [transpose v] -> [flash attention v3] -> [gemm_bt out]
// ws (bf16): qkv[16384][3072] | vT[4][1024][4096] | ao[16384][1024]  = 160 MB

typedef unsigned short u16;
typedef float f32x4 __attribute__((ext_vector_type(4)));
typedef __bf16 bf16x8 __attribute__((ext_vector_type(8)));

__device__ __forceinline__ u16 f2bf(float f) {
  __bf16 h = (__bf16)f;
  return __builtin_bit_cast(u16, h);
}

// ---------------------------------------------------------------------------
// C[M][N] = A[M][K] @ B[N][K]^T  (bf16 MFMA, fp32 accumulate). TA/TB/TC are
// float or u16(bf16); fp32 sources are converted to bf16 during LDS staging.
// ---------------------------------------------------------------------------
template <typename TA, typename TB, typename TC>
__global__ __launch_bounds__(256) void gemm_bt(const TA* __restrict__ A,
                                               const TB* __restrict__ B,
                                               TC* __restrict__ C,
                                               int M, int N, int K) {
  constexpr int LDT = 40;
  __shared__ u16 As[128 * LDT];
  __shared__ u16 Bs[128 * LDT];
  const int tid = threadIdx.x;
  const int lane = tid & 63, wv = tid >> 6;
  const int l15 = lane & 15, l4 = lane >> 4;
  const int bm = blockIdx.y * 128, bn = blockIdx.x * 128;
  const int wm = (wv >> 1) * 64, wn = (wv & 1) * 64;
  const int srow = tid >> 1, scol = (tid & 1) * 16;
  const TA* ag = A + (size_t)(bm + srow) * K + scol;
  const TB* bg = B + (size_t)(bn + srow) * K + scol;

  float4 paf[4], pbf[4];
  uint4 pau[2], pbu[2];

  auto loadA = [&](int off) {
    if constexpr (sizeof(TA) == 4) {
#pragma unroll
      for (int i = 0; i < 4; ++i) paf[i] = *(const float4*)((const float*)ag + off + 4 * i);
    } else {
      pau[0] = *(const uint4*)((const u16*)ag + off);
      pau[1] = *(const uint4*)((const u16*)ag + off + 8);
    }
  };
  auto loadB = [&](int off) {
    if constexpr (sizeof(TB) == 4) {
#pragma unroll
      for (int i = 0; i < 4; ++i) pbf[i] = *(const float4*)((const float*)bg + off + 4 * i);
    } else {
      pbu[0] = *(const uint4*)((const u16*)bg + off);
      pbu[1] = *(const uint4*)((const u16*)bg + off + 8);
    }
  };
  auto storeA = [&](u16* dst) {
    if constexpr (sizeof(TA) == 4) {
      u16 t[16];
#pragma unroll
      for (int i = 0; i < 4; ++i) {
        t[i * 4 + 0] = f2bf(paf[i].x); t[i * 4 + 1] = f2bf(paf[i].y);
        t[i * 4 + 2] = f2bf(paf[i].z); t[i * 4 + 3] = f2bf(paf[i].w);
      }
      *(uint4*)dst = *(const uint4*)&t[0];
      *(uint4*)(dst + 8) = *(const uint4*)&t[8];
    } else {
      *(uint4*)dst = pau[0];
      *(uint4*)(dst + 8) = pau[1];
    }
  };
  auto storeB = [&](u16* dst) {
    if constexpr (sizeof(TB) == 4) {
      u16 t[16];
#pragma unroll
      for (int i = 0; i < 4; ++i) {
        t[i * 4 + 0] = f2bf(pbf[i].x); t[i * 4 + 1] = f2bf(pbf[i].y);
        t[i * 4 + 2] = f2bf(pbf[i].z); t[i * 4 + 3] = f2bf(pbf[i].w);
      }
      *(uint4*)dst = *(const uint4*)&t[0];
      *(uint4*)(dst + 8) = *(const uint4*)&t[8];
    } else {
      *(uint4*)dst = pbu[0];
      *(uint4*)(dst + 8) = pbu[1];
    }
  };

  f32x4 acc[4][4] = {};
  loadA(0);
  loadB(0);

  for (int k0 = 0; k0 < K; k0 += 32) {
    __syncthreads();
    storeA(&As[srow * LDT + scol]);
    storeB(&Bs[srow * LDT + scol]);
    __syncthreads();
    if (k0 + 32 < K) {
      loadA(k0 + 32);
      loadB(k0 + 32);
    }
    bf16x8 af[4], bfr[4];
#pragma unroll
    for (int t = 0; t < 4; ++t)
      af[t] = *(const bf16x8*)&As[(wm + t * 16 + l15) * LDT + l4 * 8];
#pragma unroll
    for (int t = 0; t < 4; ++t)
      bfr[t] = *(const bf16x8*)&Bs[(wn + t * 16 + l15) * LDT + l4 * 8];
#pragma unroll
    for (int mt = 0; mt < 4; ++mt)
#pragma unroll
      for (int nt = 0; nt < 4; ++nt)
        acc[mt][nt] = __builtin_amdgcn_mfma_f32_16x16x32_bf16(af[mt], bfr[nt], acc[mt][nt], 0, 0, 0);
  }

#pragma unroll
  for (int mt = 0; mt < 4; ++mt)
#pragma unroll
    for (int nt = 0; nt < 4; ++nt) {
      const int row = bm + wm + mt * 16 + l4 * 4;
      const int col = bn + wn + nt * 16 + l15;
#pragma unroll
      for (int r = 0; r < 4; ++r) {
        if constexpr (sizeof(TC) == 4)
          C[(size_t)(row + r) * N + col] = acc[mt][nt][r];
        else
          C[(size_t)(row + r) * N + col] = f2bf(acc[mt][nt][r]);
      }
    }
}

// ---------------------------------------------------------------------------
// vT[b][c][s] = qkv[b*T + s][2048 + c]   (64x64 LDS tiles, bf16)
// ---------------------------------------------------------------------------
__global__ __launch_bounds__(256) void transpose_v(const u16* __restrict__ qkv,
                                                   u16* __restrict__ vT) {
  __shared__ u16 Ts[64][72];
  const int b = blockIdx.z;
  const int s0 = blockIdx.x * 64, c0 = blockIdx.y * 64;
  const int tid = threadIdx.x;
#pragma unroll
  for (int i = 0; i < 2; ++i) {
    const int k = tid + 256 * i;
    const int sr = k >> 3, c8 = (k & 7) * 8;
    uint4 val = *(const uint4*)(qkv + ((size_t)(b * 4096 + s0 + sr)) * 3072 + 2048 + c0 + c8);
    const u16* e = (const u16*)&val;
#pragma unroll
    for (int j = 0; j < 8; ++j) Ts[c8 + j][sr] = e[j];
  }
  __syncthreads();
#pragma unroll
  for (int i = 0; i < 2; ++i) {
    const int k = tid + 256 * i;
    const int cr = k >> 3, s8 = (k & 7) * 8;
    uint4 val = *(const uint4*)&Ts[cr][s8];
    *(uint4*)(vT + ((size_t)b * 1024 + c0 + cr) * 4096 + s0 + s8) = val;
  }
}

// ---------------------------------------------------------------------------
// Flash attention v3. 512 thr (8 waves), 1 WG per (b, 64-row Q-tile),
// key tile 256. No K staging: K/V fragments load DIRECT from global,
// double-buffered against MFMA (no barrier gates the K stream). Q staged in
// LDS per 256-wide D-chunk (4 chunks, cyclic prefetch; Q identical across
// tiles). Softmax fully in registers on sacc + 1KB LDS cross-wave combine.
// LDS ~70 KB; __launch_bounds__(512,1) -> no spill (acc 128 + sacc 32 AGPRs).
// ---------------------------------------------------------------------------
__global__ __launch_bounds__(512, 1) void flash_attn(const u16* __restrict__ qkv,
                                                     const u16* __restrict__ vT,
                                                     u16* __restrict__ ao) {
  __shared__ u16 Qs[64][264];   // 33.8 KB, pad->row stride 132 words (conflict-floor)
  __shared__ u16 Pb[64][264];   // 33.8 KB
  __shared__ float Sm[8][32];   // per-wave row-max partials
  __shared__ float Sl[8][32];   // per-wave row-sum partials
  __shared__ float Al[64];      // alpha / inv-l broadcast

  const int tid = threadIdx.x;
  const int lane = tid & 63, wid = tid >> 6;
  const int l15 = lane & 15, l4 = lane >> 4;
  const int wr = wid >> 2, wc = wid & 3;   // S block: rows 32*wr.., cols 64*wc..
  const int b = blockIdx.x & 3;
  const int qt = 63 - (blockIdx.x >> 2);   // LPT: big Q-tiles first
  const int t0 = qt * 64;
  const size_t base = (size_t)b * 4096;
  const u16* vTb = vT + (size_t)b * 1024 * 4096;

  const int qsr = tid >> 3, qsc = (tid & 7) * 32;  // Q stage: 64 rows x 256 cols
  const u16* qg = qkv + (base + t0 + qsr) * 3072 + qsc;

  f32x4 acc[4][8] = {};  // O: rows rg*16+l4*4+r, cols wid*128+nt*16+l15
  float m_run[2][4], l_run[2][4];
#pragma unroll
  for (int rg = 0; rg < 2; ++rg)
#pragma unroll
    for (int r = 0; r < 4; ++r) { m_run[rg][r] = -1e30f; l_run[rg][r] = 0.0f; }

  uint4 pq[4];
#pragma unroll
  for (int i = 0; i < 4; ++i) pq[i] = *(const uint4*)(qg + 8 * i);  // chunk 0

  const int ntiles = (qt >> 2) + 1;

  for (int tile = 0; tile < ntiles; ++tile) {
    const int ks0 = tile * 256;
    f32x4 sacc[2][4] = {};  // S: rows wr*32+rg*16+l4*4+r, cols wc*64+nt*16+l15

    // ---- Phase 1: S = Q @ K^T, 4 D-chunks of 256; K direct from global ----
    for (int qc = 0; qc < 4; ++qc) {
      __syncthreads();  // Qs free (also protects Pb of prev tile at qc==0)
#pragma unroll
      for (int i = 0; i < 4; ++i) *(uint4*)&Qs[qsr][qsc + 8 * i] = pq[i];
      __syncthreads();
      {
        const int qn = (qc + 1) & 3;  // cyclic: Q identical across tiles
#pragma unroll
        for (int i = 0; i < 4; ++i) pq[i] = *(const uint4*)(qg + qn * 256 + 8 * i);
      }
      const u16* kg0 = qkv + (base + ks0 + wc * 64 + l15) * 3072 + 1024 + qc * 256 + l4 * 8;
      bf16x8 kf[2][4];
#pragma unroll
      for (int nt = 0; nt < 4; ++nt)
        kf[0][nt] = *(const bf16x8*)(kg0 + nt * 16 * 3072);
#pragma unroll
      for (int kb = 0; kb < 8; ++kb) {
        const int cur = kb & 1, nxt = cur ^ 1;
        if (kb < 7) {
#pragma unroll
          for (int nt = 0; nt < 4; ++nt)
            kf[nxt][nt] = *(const bf16x8*)(kg0 + (kb + 1) * 32 + nt * 16 * 3072);
        }
        const bf16x8 af0 = *(const bf16x8*)&Qs[wr * 32 + l15][kb * 32 + l4 * 8];
        const bf16x8 af1 = *(const bf16x8*)&Qs[wr * 32 + 16 + l15][kb * 32 + l4 * 8];
#pragma unroll
        for (int nt = 0; nt < 4; ++nt) {
          sacc[0][nt] = __builtin_amdgcn_mfma_f32_16x16x32_bf16(af0, kf[cur][nt], sacc[0][nt], 0, 0, 0);
          sacc[1][nt] = __builtin_amdgcn_mfma_f32_16x16x32_bf16(af1, kf[cur][nt], sacc[1][nt], 0, 0, 0);
        }
      }
    }

    // ---- Phase 2: in-register online softmax ----
    const float scale = 0.03125f;  // 1/sqrt(1024)
    float rmax[2][4];
#pragma unroll
    for (int rg = 0; rg < 2; ++rg)
#pragma unroll
      for (int r = 0; r < 4; ++r) {
        const int row = t0 + wr * 32 + rg * 16 + l4 * 4 + r;
        float m = -1e30f;
#pragma unroll
        for (int nt = 0; nt < 4; ++nt) {
          const int col = ks0 + wc * 64 + nt * 16 + l15;
          float s = sacc[rg][nt][r] * scale;
          if (col > row) s = -1e30f;  // causal mask
          sacc[rg][nt][r] = s;
          m = fmaxf(m, s);
        }
        rmax[rg][r] = m;
      }
#pragma unroll
    for (int mk = 1; mk <= 8; mk <<= 1)
#pragma unroll
      for (int rg = 0; rg < 2; ++rg)
#pragma unroll
        for (int r = 0; r < 4; ++r)
          rmax[rg][r] = fmaxf(rmax[rg][r], __shfl_xor(rmax[rg][r], mk));
    if (l15 == 0) {
#pragma unroll
      for (int rg = 0; rg < 2; ++rg)
#pragma unroll
        for (int r = 0; r < 4; ++r) Sm[wid][rg * 16 + l4 * 4 + r] = rmax[rg][r];
    }
    __syncthreads();
    float al[2][4];
#pragma unroll
    for (int rg = 0; rg < 2; ++rg)
#pragma unroll
      for (int r = 0; r < 4; ++r) {
        const int lr32 = rg * 16 + l4 * 4 + r;
        const float mt = fmaxf(fmaxf(Sm[wr * 4 + 0][lr32], Sm[wr * 4 + 1][lr32]),
                               fmaxf(Sm[wr * 4 + 2][lr32], Sm[wr * 4 + 3][lr32]));
        const float mn = fmaxf(m_run[rg][r], mt);
        al[rg][r] = __expf(m_run[rg][r] - mn);
        m_run[rg][r] = mn;
      }
    float rsum[2][4];
#pragma unroll
    for (int rg = 0; rg < 2; ++rg)
#pragma unroll
      for (int r = 0; r < 4; ++r) {
        const int lrow = wr * 32 + rg * 16 + l4 * 4 + r;
        float s = 0.0f;
#pragma unroll
        for (int nt = 0; nt < 4; ++nt) {
          const float pe = __expf(sacc[rg][nt][r] - m_run[rg][r]);
          s += pe;
          Pb[lrow][wc * 64 + nt * 16 + l15] = f2bf(pe);
        }
        rsum[rg][r] = s;
      }
#pragma unroll
    for (int mk = 1; mk <= 8; mk <<= 1)
#pragma unroll
      for (int rg = 0; rg < 2; ++rg)
#pragma unroll
        for (int r = 0; r < 4; ++r) rsum[rg][r] += __shfl_xor(rsum[rg][r], mk);
    if (l15 == 0) {
#pragma unroll
      for (int rg = 0; rg < 2; ++rg)
#pragma unroll
        for (int r = 0; r < 4; ++r) Sl[wid][rg * 16 + l4 * 4 + r] = rsum[rg][r];
      if (wc == 0) {
#pragma unroll
        for (int rg = 0; rg < 2; ++rg)
#pragma unroll
          for (int r = 0; r < 4; ++r) Al[wr * 32 + rg * 16 + l4 * 4 + r] = al[rg][r];
      }
    }
    __syncthreads();
#pragma unroll
    for (int rg = 0; rg < 2; ++rg)
#pragma unroll
      for (int r = 0; r < 4; ++r) {
        const int lr32 = rg * 16 + l4 * 4 + r;
        const float tot = (Sl[wr * 4 + 0][lr32] + Sl[wr * 4 + 1][lr32]) +
                          (Sl[wr * 4 + 2][lr32] + Sl[wr * 4 + 3][lr32]);
        l_run[rg][r] = al[rg][r] * l_run[rg][r] + tot;
      }

    // ---- Phase 3: rescale O, then PV (V direct from global, dbuf'd) ----
    {
      float avv[4][4];
      int need = 0;
#pragma unroll
      for (int rg = 0; rg < 4; ++rg) {
        const float4 a4 = *(const float4*)&Al[rg * 16 + l4 * 4];
        avv[rg][0] = a4.x; avv[rg][1] = a4.y; avv[rg][2] = a4.z; avv[rg][3] = a4.w;
        need |= (a4.x != 1.0f) | (a4.y != 1.0f) | (a4.z != 1.0f) | (a4.w != 1.0f);
      }
      if (__any(need)) {
#pragma unroll
        for (int rg = 0; rg < 4; ++rg)
#pragma unroll
          for (int nt = 0; nt < 8; ++nt)
#pragma unroll
            for (int r = 0; r < 4; ++r) acc[rg][nt][r] *= avv[rg][r];
      }
      const u16* vg0 = vTb + (size_t)(wid * 128 + l15) * 4096 + ks0 + l4 * 8;
#pragma unroll
      for (int kb = 0; kb < 8; ++kb) {
        bf16x8 pf[4];
#pragma unroll
        for (int rg = 0; rg < 4; ++rg)
          pf[rg] = *(const bf16x8*)&Pb[rg * 16 + l15][kb * 32 + l4 * 8];
#pragma unroll
        for (int nt = 0; nt < 8; ++nt) {
          const bf16x8 vf = *(const bf16x8*)(vg0 + (size_t)nt * 16 * 4096 + kb * 32);
#pragma unroll
          for (int rg = 0; rg < 4; ++rg)
            acc[rg][nt] = __builtin_amdgcn_mfma_f32_16x16x32_bf16(pf[rg], vf, acc[rg][nt], 0, 0, 0);
        }
      }
    }
  }

  // ---- epilogue: O / l ----
  __syncthreads();
  if (l15 == 0 && wc == 0) {
#pragma unroll
    for (int rg = 0; rg < 2; ++rg)
#pragma unroll
      for (int r = 0; r < 4; ++r)
        Al[wr * 32 + rg * 16 + l4 * 4 + r] = 1.0f / l_run[rg][r];
  }
  __syncthreads();
  float ivv[4][4];
#pragma unroll
  for (int rg = 0; rg < 4; ++rg) {
    const float4 a4 = *(const float4*)&Al[rg * 16 + l4 * 4];
    ivv[rg][0] = a4.x; ivv[rg][1] = a4.y; ivv[rg][2] = a4.z; ivv[rg][3] = a4.w;
  }
#pragma unroll
  for (int rg = 0; rg < 4; ++rg)
#pragma unroll
    for (int nt = 0; nt < 8; ++nt) {
      const size_t rbase = (base + t0 + rg * 16 + l4 * 4) * 1024 + wid * 128 + nt * 16 + l15;
#pragma unroll
      for (int r = 0; r < 4; ++r)
        ao[rbase + (size_t)r * 1024] = f2bf(acc[rg][nt][r] * ivv[rg][r]);
    }
}

// ---------------------------------------------------------------------------
extern "C" void kernel_launch(void* const* d_in, const int* in_sizes, int n_in,
                              void* d_out, int out_size, void* d_ws, size_t ws_size,
                              hipStream_t stream) {
  const float* x     = (const float*)d_in[0];   // [4,4096,1024] fp32
  // d_in[1] = causal mask: ignored (computed analytically)
  const float* w_qkv = (const float*)d_in[2];   // [3072,1024] fp32
  const float* w_out = (const float*)d_in[3];   // [1024,1024] fp32
  float* out = (float*)d_out;                   // [4,4096,1024] fp32

  u16* qkv = (u16*)d_ws;                        // 16384*3072 bf16
  u16* vT  = qkv + (size_t)16384 * 3072;        // 4*1024*4096 bf16
  u16* ao  = vT + (size_t)4 * 1024 * 4096;      // 16384*1024 bf16

  gemm_bt<float, float, u16><<<dim3(24, 128), 256, 0, stream>>>(x, w_qkv, qkv, 16384, 3072, 1024);
  transpose_v<<<dim3(64, 16, 4), 256, 0, stream>>>(qkv, vT);
  flash_attn<<<dim3(256), 512, 0, stream>>>(qkv, vT, ao);
  gemm_bt<u16, float, float><<<dim3(8, 128), 256, 0, stream>>>(ao, w_out, out, 16384, 1024, 1024);
}